// Round 9
// baseline (171.108 us; speedup 1.0000x reference)
//
#include <hip/hip_runtime.h>

// Balloon-Windkessel BOLD, explicit Euler, T=1000, B=16384.
// alpha==1 decouples the system: (s,f) is an affine scan with constant 2x2
// matrix A; v,q are affine scans given f; only E(f) is nonlinear.
//
// ROUND-9 (= r8 resubmit; r8 bench was an infra failure, no data).
// TWO-KERNEL WALK. r7 showed the harness's inter-iteration 268 MB
// fillBuffer flushes L3, so every pass over the 64 MB noise pays HBM;
// pass count + launch count dominate. r7 = 3 passes + 5 launches
// ~= 50us/iter. This version: 2 passes + 2 launches.
//   k_aggsf: full-occupancy pass over z -> per-(chunk,sim) fp32 (s,f)
//            chunk aggregates (5.2 MB ws).                     (~10us)
//   k_walk : ONE THREAD PER SIM (256 blocks x 64 thr = 1 wave/SIMD on
//            all 1024 SIMDs). Serially over 40 chunks: f64 chunk-start
//            (s,f) update from aggregates (token-identical to r7's
//            validated k_scansf), then 25 fp32 steps with EXACT
//            continuous v,q (no scan approximation at all) + emit y.
//            z double-buffered in registers (2x25 VGPR, static indexing,
//            256-VGPR budget at 1 wave/SIMD); chunk c+1 loads issue
//            before chunk c compute.                           (~15-25us)
// v,q are stepped continuously across all 1000 steps (the reference
// recurrence itself) -> strictly tighter than the scan approximation.
// (s,f) chunk starts: f64 scan of fp32 aggregates, validated at 9.5e-7.
// Fallback: proven r0 monolithic kernel if ws too small.

#define BATCH     16384
#define DT        0.01f
#define NOISE_AMP 0.01f
#define V0        0.02f
#define CHUNKS    40
#define CL        25          // 40 * 25 = 1000 steps
#define TPB       256         // aggregate kernel block size
#define WTPB      64          // walk kernel block size (1 wave)

#if __has_builtin(__builtin_amdgcn_exp2f)
#define EXP2F(x) __builtin_amdgcn_exp2f(x)
#else
#define EXP2F(x) exp2f(x)
#endif

__device__ __forceinline__ float uf(float x) {
    return __uint_as_float(__builtin_amdgcn_readfirstlane(__float_as_uint(x)));
}

struct D22 { double a, b, c, d; };
__device__ __forceinline__ D22 dmul(D22 x, D22 y) {
    D22 r;
    r.a = x.a * y.a + x.b * y.c;  r.b = x.a * y.b + x.b * y.d;
    r.c = x.c * y.a + x.d * y.c;  r.d = x.c * y.b + x.d * y.d;
    return r;
}

__device__ __forceinline__ D22 a25_of(float sigma, float mu) {
    D22 A; A.a = 1.0 - 0.01 * (double)sigma; A.b = -0.01 * (double)mu;
           A.c = 0.01;                       A.d = 1.0;
    D22 A2 = dmul(A, A), A4 = dmul(A2, A2), A8 = dmul(A4, A4);
    D22 A16 = dmul(A8, A8);
    return dmul(dmul(A16, A8), A);                  // A^25
}

// ---------------------------------------------------------------------------
// k_aggsf: per-(chunk,sim) fp32 (s,f) chunk aggregate. (validated r7)
// ---------------------------------------------------------------------------
__global__ __launch_bounds__(TPB, 8) void k_aggsf(
    const float* __restrict__ noise,
    const float* __restrict__ p_sigma,
    const float* __restrict__ p_mu,
    float* __restrict__ wsS, float* __restrict__ wsF)
{
    const int sim = blockIdx.x * TPB + threadIdx.x;
    const int cc  = blockIdx.y;

    const float sigma = uf(p_sigma[0]);
    const float mu    = uf(p_mu[0]);
    const float as_   = 1.0f - DT * sigma;
    const float dtn   = DT * NOISE_AMP;
    const float dtm   = DT * mu;

    const float* zp = noise + cc * (CL * BATCH) + sim;
    float rs = 0.0f, rf = 0.0f;
#pragma unroll
    for (int j = 0; j < CL; ++j) {
        const float z = zp[j * BATCH];
        const float u = __builtin_fmaf(dtn, z, dtm);
        const float t = __builtin_fmaf(as_, rs, __builtin_fmaf(-dtm, rf, u));
        rf = __builtin_fmaf(DT, rs, rf);
        rs = t;
    }
    wsS[cc * BATCH + sim] = rs;
    wsF[cc * BATCH + sim] = rf;
}

// ---------------------------------------------------------------------------
// k_walk: one thread per sim; f64 (s,f) chunk-start scan + exact fp32 v,q
// walk + emit, all in one pass over z.
// ---------------------------------------------------------------------------
__global__ __launch_bounds__(WTPB) void k_walk(
    const float* __restrict__ noise,
    const float* __restrict__ p_sigma,
    const float* __restrict__ p_mu,
    const float* __restrict__ p_lamb,
    const float* __restrict__ p_beta,
    const float* __restrict__ p_psi,
    const float* __restrict__ p_phi,
    const float* __restrict__ p_chi,
    const float* __restrict__ wsS, const float* __restrict__ wsF,
    float* __restrict__ out)
{
    const int sim = blockIdx.x * WTPB + threadIdx.x;
    const float* zcol = noise + sim;
    float*       ocol = out   + sim;

    // issue chunk-0 z loads FIRST; scalar setup below overlaps the latency
    float zA[CL], zB[CL];
#pragma unroll
    for (int j = 0; j < CL; ++j) zA[j] = zcol[j * BATCH];

    const float sigma = uf(p_sigma[0]);
    const float mu    = uf(p_mu[0]);
    const float lamb  = uf(p_lamb[0]);
    const float beta  = uf(p_beta[0]);
    const float psi   = uf(p_psi[0]);
    const float phi   = uf(p_phi[0]);
    const float chi   = uf(p_chi[0]);

    const float as_   = 1.0f - DT * sigma;
    const float dtn   = DT * NOISE_AMP;
    const float dtm   = DT * mu;
    const float dt_il = uf((float)(0.01 / (double)lamb));
    const float av    = 1.0f - dt_il;
    const float kq    = uf(dt_il / beta);
    const float lc    = uf(log2f(1.0f - beta));
    const float c0 = V0 * (phi + psi + chi), c1 = V0 * phi, c2 = V0 * psi, c3 = V0 * chi;

    const D22 P = a25_of(sigma, mu);

    double sd = 0.0, fd = 1.0;          // f64 chunk-start (s,f) carry
    float  v  = 1.0f, q = 1.0f;         // exact continuous fp32 v,q

    // one chunk: fp32 (s,f) replay from f64 start; exact v,q step; emit y
#define WALK_CHUNK(ZR, CBASE)                                               \
    {                                                                       \
        float s = (float)sd, f = (float)fd;                                 \
        float* op = ocol + (size_t)(CBASE) * CL * BATCH;                    \
        _Pragma("unroll")                                                   \
        for (int j = 0; j < CL; ++j) {                                      \
            const float z    = ZR[j];                                       \
            const float invf = __builtin_amdgcn_rcpf(f);                    \
            const float e2   = EXP2F(lc * invf);                            \
            const float t1   = __builtin_fmaf(-f, e2, f);                   \
            const float vn   = __builtin_fmaf(av, v, dt_il * f);            \
            const float qn   = __builtin_fmaf(av, q, kq * t1);              \
            const float s2   = __builtin_fmaf(as_, s,                       \
                               __builtin_fmaf(dtn, z,                       \
                               __builtin_fmaf(-dtm, f, dtm)));              \
            f = __builtin_fmaf(DT, s, f);                                   \
            s = s2;                                                         \
            const float invv = __builtin_amdgcn_rcpf(vn);                   \
            const float y = __builtin_fmaf(-c2, qn * invv,                  \
                            __builtin_fmaf(-c3, vn,                         \
                            __builtin_fmaf(-c1, qn, c0)));                  \
            __builtin_nontemporal_store(y, op + j * BATCH);                 \
            v = vn; q = qn;                                                 \
        }                                                                   \
    }

    for (int c = 0; c < CHUNKS; c += 2) {
        // aggregate loads for this pair (independent; issue early)
        const float rsA = wsS[c * BATCH + sim];
        const float rfA = wsF[c * BATCH + sim];
        const float rsB = wsS[(c + 1) * BATCH + sim];
        const float rfB = wsF[(c + 1) * BATCH + sim];

        // prefetch chunk c+1's z while walking chunk c
        {
            const float* zp = zcol + (size_t)(c + 1) * CL * BATCH;
#pragma unroll
            for (int j = 0; j < CL; ++j) zB[j] = zp[j * BATCH];
        }

        WALK_CHUNK(zA, c);
        // advance f64 (s,f) carry past chunk c (identical to r7 k_scansf)
        {
            const double ns = P.a * sd + P.b * fd + (double)rsA;
            fd              = P.c * sd + P.d * fd + (double)rfA;
            sd = ns;
        }

        // prefetch chunk c+2's z while walking chunk c+1
        if (c + 2 < CHUNKS) {
            const float* zp = zcol + (size_t)(c + 2) * CL * BATCH;
#pragma unroll
            for (int j = 0; j < CL; ++j) zA[j] = zp[j * BATCH];
        }

        WALK_CHUNK(zB, c + 1);
        {
            const double ns = P.a * sd + P.b * fd + (double)rsB;
            fd              = P.c * sd + P.d * fd + (double)rfB;
            sd = ns;
        }
    }
#undef WALK_CHUNK
}

// ---------------------------------------------------------------------------
// Fallback: proven round-0 monolithic kernel (47us/dispatch).
// ---------------------------------------------------------------------------
#define CH0   20
#define CL0   50
#define GS0   32
#define NT0   (CH0 * GS0)   // 640

__global__ __launch_bounds__(NT0, 5) void balloon_mono(
    const float* __restrict__ noise,
    const float* __restrict__ p_sigma,
    const float* __restrict__ p_mu,
    const float* __restrict__ p_lamb,
    const float* __restrict__ p_beta,
    const float* __restrict__ p_psi,
    const float* __restrict__ p_phi,
    const float* __restrict__ p_chi,
    float* __restrict__ out)
{
    const int tid = threadIdx.x;
    const int g   = tid & (GS0 - 1);
    const int cc  = tid >> 5;
    const int sim = blockIdx.x * GS0 + g;

    const float sigma = uf(p_sigma[0]);
    const float mu    = uf(p_mu[0]);
    const float lamb  = uf(p_lamb[0]);
    const float beta  = uf(p_beta[0]);
    const float psi   = uf(p_psi[0]);
    const float phi   = uf(p_phi[0]);
    const float chi   = uf(p_chi[0]);

    const float as_   = 1.0f - DT * sigma;
    const float dtn   = DT * NOISE_AMP;
    const float dtm   = DT * mu;
    const float dt_il = uf((float)(0.01 / (double)lamb));
    const float av    = 1.0f - dt_il;
    const float kq    = uf(dt_il / beta);
    const float lc    = uf(log2f(1.0f - beta));
    const float c0 = V0 * (phi + psi + chi), c1 = V0 * phi, c2 = V0 * psi, c3 = V0 * chi;

    D22 A; A.a = 1.0 - 0.01 * (double)sigma; A.b = -0.01 * (double)mu;
           A.c = 0.01;                       A.d = 1.0;
    D22 A2 = dmul(A, A), A4 = dmul(A2, A2), A8 = dmul(A4, A4);
    D22 A16 = dmul(A8, A8), A32 = dmul(A16, A16);
    D22 P = dmul(dmul(A32, A16), A2);               // A^50
    double avd = 1.0 - 0.01 / (double)lamb;
    double av2 = avd * avd, av4 = av2 * av2, av8 = av4 * av4;
    double av16 = av8 * av8, av32 = av16 * av16;
    double ap = av32 * av16 * av2;                  // av^50

    float M11[5], M12[5], M21[5], M22[5], AVP[5];
#pragma unroll
    for (int j = 0; j < 5; ++j) {
        M11[j] = uf((float)P.a); M12[j] = uf((float)P.b);
        M21[j] = uf((float)P.c); M22[j] = uf((float)P.d);
        AVP[j] = uf((float)ap);
        P = dmul(P, P); ap = ap * ap;
    }

    float ws_h = 0.0f, wf_h = 1.0f, avc = 1.0f;
#pragma unroll
    for (int j = 0; j < 5; ++j) {
        if ((cc >> j) & 1) {
            float t = __builtin_fmaf(M11[j], ws_h, M12[j] * wf_h);
            wf_h = __builtin_fmaf(M21[j], ws_h, M22[j] * wf_h);
            ws_h = t;
            avc *= AVP[j];
        }
    }

    __shared__ float sA[NT0];
    __shared__ float sB[NT0];

    const float* zp = noise + cc * (CL0 * BATCH) + sim;

    float rs = 0.0f, rf = 0.0f;
#pragma unroll 10
    for (int j = 0; j < CL0; ++j) {
        const float z = zp[j * BATCH];
        const float u = __builtin_fmaf(dtn, z, dtm);
        const float t = __builtin_fmaf(as_, rs, __builtin_fmaf(-dtm, rf, u));
        rf = __builtin_fmaf(DT, rs, rf);
        rs = t;
    }

    sA[tid] = rs; sB[tid] = rf;
    __syncthreads();
#pragma unroll
    for (int j = 0; j < 5; ++j) {
        const int off = 1 << j;
        float ns = 0.0f, nf = 0.0f;
        const bool has = (cc >= off);
        if (has) { ns = sA[tid - off * GS0]; nf = sB[tid - off * GS0]; }
        __syncthreads();
        if (has) {
            rs = __builtin_fmaf(M11[j], ns, __builtin_fmaf(M12[j], nf, rs));
            rf = __builtin_fmaf(M21[j], ns, __builtin_fmaf(M22[j], nf, rf));
            sA[tid] = rs; sB[tid] = rf;
        }
        __syncthreads();
    }
    float s0 = ws_h, f0 = wf_h;
    if (cc > 0) { s0 += sA[tid - GS0]; f0 += sB[tid - GS0]; }
    __syncthreads();

    float s = s0, f = f0, Rv = 0.0f, Rq = 0.0f;
#pragma unroll 10
    for (int j = 0; j < CL0; ++j) {
        const float z    = zp[j * BATCH];
        const float invf = __builtin_amdgcn_rcpf(f);
        const float e2   = EXP2F(lc * invf);
        const float t1   = __builtin_fmaf(-f, e2, f);
        Rv = __builtin_fmaf(av, Rv, dt_il * f);
        Rq = __builtin_fmaf(av, Rq, kq * t1);
        const float s2 = __builtin_fmaf(as_, s,
                         __builtin_fmaf(dtn, z,
                         __builtin_fmaf(-dtm, f, dtm)));
        f = __builtin_fmaf(DT, s, f);
        s = s2;
    }

    sA[tid] = Rv; sB[tid] = Rq;
    __syncthreads();
#pragma unroll
    for (int j = 0; j < 5; ++j) {
        const int off = 1 << j;
        float nv = 0.0f, nq = 0.0f;
        const bool has = (cc >= off);
        if (has) { nv = sA[tid - off * GS0]; nq = sB[tid - off * GS0]; }
        __syncthreads();
        if (has) {
            Rv = __builtin_fmaf(AVP[j], nv, Rv);
            Rq = __builtin_fmaf(AVP[j], nq, Rq);
            sA[tid] = Rv; sB[tid] = Rq;
        }
        __syncthreads();
    }
    float v = avc, q = avc;
    if (cc > 0) { v += sA[tid - GS0]; q += sB[tid - GS0]; }

    s = s0; f = f0;
    float* op = out + cc * (CL0 * BATCH) + sim;
#pragma unroll 10
    for (int j = 0; j < CL0; ++j) {
        const float z    = zp[j * BATCH];
        const float invf = __builtin_amdgcn_rcpf(f);
        const float e2   = EXP2F(lc * invf);
        const float t1   = __builtin_fmaf(-f, e2, f);
        const float vn   = __builtin_fmaf(av, v, dt_il * f);
        const float qn   = __builtin_fmaf(av, q, kq * t1);
        const float s2 = __builtin_fmaf(as_, s,
                         __builtin_fmaf(dtn, z,
                         __builtin_fmaf(-dtm, f, dtm)));
        f = __builtin_fmaf(DT, s, f);
        s = s2;

        const float invv = __builtin_amdgcn_rcpf(vn);
        const float y = __builtin_fmaf(-c2, qn * invv,
                        __builtin_fmaf(-c3, vn,
                        __builtin_fmaf(-c1, qn, c0)));
        op[j * BATCH] = y;
        v = vn; q = qn;
    }
}

extern "C" void kernel_launch(void* const* d_in, const int* in_sizes, int n_in,
                              void* d_out, int out_size, void* d_ws, size_t ws_size,
                              hipStream_t stream) {
    const float* noise   = (const float*)d_in[0];
    const float* p_sigma = (const float*)d_in[1];
    const float* p_mu    = (const float*)d_in[2];
    const float* p_lamb  = (const float*)d_in[3];
    const float* p_beta  = (const float*)d_in[4];
    const float* p_psi   = (const float*)d_in[5];
    const float* p_phi   = (const float*)d_in[6];
    const float* p_chi   = (const float*)d_in[7];

    const size_t narr = (size_t)CHUNKS * BATCH;            // 655360 floats
    const size_t need = 2 * narr * sizeof(float);          // 5.24 MB
    if (d_ws != nullptr && ws_size >= need) {
        float* wsS = (float*)d_ws;
        float* wsF = wsS + narr;

        k_aggsf<<<dim3(BATCH / TPB, CHUNKS), TPB, 0, stream>>>(
            noise, p_sigma, p_mu, wsS, wsF);
        k_walk<<<BATCH / WTPB, WTPB, 0, stream>>>(
            noise, p_sigma, p_mu, p_lamb, p_beta, p_psi, p_phi, p_chi,
            wsS, wsF, (float*)d_out);
    } else {
        balloon_mono<<<BATCH / GS0, NT0, 0, stream>>>(
            noise, p_sigma, p_mu, p_lamb, p_beta, p_psi, p_phi, p_chi,
            (float*)d_out);
    }
}